// Round 6
// baseline (44212.225 us; speedup 1.0000x reference)
//
#include <hip/hip_runtime.h>
#include <hip/hip_bf16.h>

#define Bn 64
#define Sn 256
#define In 512
#define Hn 80
#define Tn 600
#define Cn 512
#define LOCn 8
#define Kn 21
#define Pn 11
#define G3 1536

typedef _Float16 h2 __attribute__((ext_vector_type(2)));

// ---- ws layout (dword offsets) ----
enum : unsigned {
  OFF_WHPK     = 0u,                        // [256 kp][512 c][3 g] half2 pairs over h
  OFF_W1PK     = OFF_WHPK + 256u * 1536u,   // [256 kp][512 c]
  OFF_W2PK     = OFF_W1PK + 256u * 512u,    // [256 kp][168 j]
  OFF_WIFPK    = OFF_W2PK + 256u * 168u,    // [40 jp][512 c][3 g] frame part
  OFF_WIPREVPK = OFF_WIFPK + 40u * 1536u,   // [256 kp][512 c][3 g] prev part (fallback)
  OFF_BI       = OFF_WIPREVPK + 256u * 1536u,
  OFF_BH       = OFF_BI + 1536u,
  OFF_B1       = OFF_BH + 1536u,
  OFF_LW       = OFF_B1 + 512u,
  OFF_PW       = OFF_LW + 176u,
  OFF_DW       = OFF_PW + 2048u,
  OFF_DB       = OFF_DW + 2048u,
  OFF_AGG      = OFF_DB + 256u,
  OFF_PRI      = OFF_AGG + 256u,
  OFF_FLAG     = OFF_PRI + 16u,
  OFF_WIPT     = 1030400u,                  // fp32 [512 i][1536 m] = wi[m][80+i]
  OFF_ENCW     = OFF_WIPT + 512u * 1536u,   // [b][128 sp][512 c][3 g] half2 pairs over s
  WS_END_ENCW  = OFF_ENCW + 64u * 128u * 1536u,
  OFF_XH       = WS_END_ENCW,               // [64][256] full-h f16 pairs
  OFF_TP       = OFF_XH + 64u * 256u,       // [64][8][512] t1 partials f32
  OFF_XE       = OFF_TP + 64u * 4096u,      // [64][256] energy f32 bits
  OFF_FLG      = OFF_XE + 64u * 256u,       // [64][32]: A at +0..3, B at +16..19
  WS_END_ALL   = OFF_FLG + 64u * 32u
};

__device__ __forceinline__ float ld_any(const void* p, long long i, int bf) {
  if (bf) {
    unsigned v = ((const unsigned short*)p)[i];
    return __uint_as_float(v << 16);
  }
  return ((const float*)p)[i];
}
__device__ __forceinline__ unsigned pack_h2(float a, float b) {
  union { h2 h; unsigned u; } x;
  x.h.x = (_Float16)a; x.h.y = (_Float16)b;
  return x.u;
}
__device__ __forceinline__ h2 u_to_h2(unsigned u) {
  union { h2 h; unsigned u; } x; x.u = u; return x.h;
}
__device__ __forceinline__ float dot2f(unsigned w, unsigned a, float acc) {
#if __has_builtin(__builtin_amdgcn_fdot2)
  return __builtin_amdgcn_fdot2(u_to_h2(w), u_to_h2(a), acc, false);
#else
  h2 wv = u_to_h2(w), av = u_to_h2(a);
  return fmaf((float)wv.x, (float)av.x, fmaf((float)wv.y, (float)av.y, acc));
#endif
}

// fine-grained device-coherent ops
__device__ __forceinline__ void st_dev(unsigned* p, unsigned v) {
  __hip_atomic_store(p, v, __ATOMIC_RELAXED, __HIP_MEMORY_SCOPE_AGENT);
}
__device__ __forceinline__ unsigned ld_dev(const unsigned* p) {
  return __hip_atomic_load(p, __ATOMIC_RELAXED, __HIP_MEMORY_SCOPE_AGENT);
}

__device__ __forceinline__ float fast_exp(float x) {
  return __builtin_amdgcn_exp2f(x * 1.4426950408889634f);
}
__device__ __forceinline__ float fast_sigmoid(float x) {
  return __builtin_amdgcn_rcpf(1.f + fast_exp(-x));
}
__device__ __forceinline__ float fast_tanh(float x) {
  float u = __builtin_amdgcn_exp2f(x * 2.8853900817779268f);
  return 1.f - 2.f * __builtin_amdgcn_rcpf(u + 1.f);
}
__device__ __forceinline__ float fast_log(float x) {
  return __builtin_amdgcn_logf(x) * 0.6931471805599453f;
}

__global__ void k_flag(const void* mask, float* ws) {
  if (threadIdx.x == 0 && blockIdx.x == 0) {
    unsigned w = *(const unsigned*)mask;
    ((int*)(ws + OFF_FLAG))[0] = (w == 0x3F803F80u) ? 1 : 0;
  }
}

__global__ void k_zero(unsigned* U) {
  int x = blockIdx.x * blockDim.x + threadIdx.x;
  if (x < 64 * 32) U[OFF_FLG + x] = 0u;
}

__global__ void k_prep(const void* wi, const void* wh, const void* gbi, const void* gbh,
                       const void* lcw, const void* lpw, const void* w1, const void* kb1,
                       const void* w2, const void* dw, const void* ddb, const void* aggw,
                       const void* pri, float* wsf, unsigned* U) {
  const int bf = ((const int*)(wsf + OFF_FLAG))[0];
  const int tid = blockIdx.x * blockDim.x + threadIdx.x;
  const int nT = gridDim.x * blockDim.x;
  for (int x = tid; x < 256 * 1536; x += nT) {
    int g = x % 3, y = x / 3, c = y % 512, kp = y / 512;
    long long r = (long long)(g * 512 + c) * Cn + 2 * kp;
    U[OFF_WHPK + x] = pack_h2(ld_any(wh, r, bf), ld_any(wh, r + 1, bf));
  }
  for (int x = tid; x < 256 * 512; x += nT) {
    int c = x % 512, kp = x / 512;
    long long r = (long long)c * Cn + 2 * kp;
    U[OFF_W1PK + x] = pack_h2(ld_any(w1, r, bf), ld_any(w1, r + 1, bf));
  }
  for (int x = tid; x < 256 * 168; x += nT) {
    int j = x % 168, kp = x / 168;
    long long r = (long long)j * Cn + 2 * kp;
    U[OFF_W2PK + x] = pack_h2(ld_any(w2, r, bf), ld_any(w2, r + 1, bf));
  }
  for (int x = tid; x < 40 * 1536; x += nT) {
    int g = x % 3, y = x / 3, c = y % 512, jp = y / 512;
    long long r = (long long)(g * 512 + c) * (In + Hn) + 2 * jp;
    U[OFF_WIFPK + x] = pack_h2(ld_any(wi, r, bf), ld_any(wi, r + 1, bf));
  }
  for (int x = tid; x < 256 * 1536; x += nT) {
    int g = x % 3, y = x / 3, c = y % 512, kp = y / 512;
    long long r = (long long)(g * 512 + c) * (In + Hn) + Hn + 2 * kp;
    U[OFF_WIPREVPK + x] = pack_h2(ld_any(wi, r, bf), ld_any(wi, r + 1, bf));
  }
  for (int x = tid; x < 512 * 1536; x += nT) {
    int i = x / 1536, m = x % 1536;
    wsf[OFF_WIPT + x] = ld_any(wi, (long long)m * (In + Hn) + Hn + i, bf);
  }
  for (int x = tid; x < G3; x += nT) wsf[OFF_BI + x] = ld_any(gbi, x, bf);
  for (int x = tid; x < G3; x += nT) wsf[OFF_BH + x] = ld_any(gbh, x, bf);
  for (int x = tid; x < Cn; x += nT) wsf[OFF_B1 + x] = ld_any(kb1, x, bf);
  for (int x = tid; x < LOCn * Kn; x += nT) wsf[OFF_LW + x] = ld_any(lcw, x, bf);
  for (int x = tid; x < 256 * LOCn; x += nT) wsf[OFF_PW + x] = ld_any(lpw, x, bf);
  for (int x = tid; x < 256 * LOCn; x += nT) wsf[OFF_DW + x] = ld_any(dw, x, bf);
  for (int x = tid; x < 256; x += nT) wsf[OFF_DB + x] = ld_any(ddb, x, bf);
  for (int x = tid; x < 256; x += nT) wsf[OFF_AGG + x] = ld_any(aggw, x, bf);
  for (int x = tid; x < Pn; x += nT) wsf[OFF_PRI + x] = ld_any(pri, x, bf);
}

__global__ __launch_bounds__(1024) void k_encw(const void* __restrict__ enc_,
                                               const float* __restrict__ wsf,
                                               unsigned* __restrict__ U) {
  const int b = blockIdx.x >> 2, chunk = blockIdx.x & 3;
  const int bf = ((const int*)(wsf + OFF_FLAG))[0];
  const int tid = threadIdx.x;
  const int r = tid >> 8, m0 = tid & 255;
  const int s0 = chunk * 64 + r * 16;
  const float* WiPT = wsf + OFF_WIPT;
  for (int g6 = 0; g6 < 6; ++g6) {
    int m = m0 + (g6 << 8);
    float acc[16];
    #pragma unroll
    for (int j = 0; j < 16; ++j) acc[j] = 0.f;
    #pragma unroll 4
    for (int i = 0; i < In; ++i) {
      float w = WiPT[(size_t)i * G3 + m];
      #pragma unroll
      for (int j = 0; j < 16; ++j)
        acc[j] = fmaf(w, ld_any(enc_, ((long long)b * Sn + (s0 + j)) * In + i, bf), acc[j]);
    }
    int cc = m & 511, gg = m >> 9;
    unsigned* dst = U + OFF_ENCW + (size_t)b * 128 * G3;
    #pragma unroll
    for (int jj = 0; jj < 8; ++jj)
      dst[(size_t)(((s0 >> 1) + jj) * 512 + cc) * 3 + gg] = pack_h2(acc[2 * jj], acc[2 * jj + 1]);
  }
}

// ---- 4-way split kernel: XCD-co-located groups, batched loads, sparse alpha ----
__global__ __launch_bounds__(1024, 4) void k_split(
    const void* __restrict__ mask_, const void* __restrict__ gt_,
    const float* __restrict__ wsf, unsigned* __restrict__ UW,
    void* __restrict__ out_) {
  // b = blk & 63, j = blk >> 6  =>  group b's 4 blocks at B = b+64j, all == b (mod 8)
  // -> same XCD under round-robin dispatch: shared L2 weight/ENCW working set.
  const int b = blockIdx.x & 63;
  const int j = blockIdx.x >> 6;
  const int tid = threadIdx.x;
  const int bf = ((const int*)(wsf + OFF_FLAG))[0];

  const float* BI = wsf + OFF_BI;
  const float* BH = wsf + OFF_BH;
  const float* B1 = wsf + OFF_B1;
  const float* lw = wsf + OFF_LW;
  const float* Pw = wsf + OFF_PW;
  const float* Dw = wsf + OFF_DW;
  const float* dbv = wsf + OFF_DB;
  const float* agg = wsf + OFF_AGG;
  const float* prw = wsf + OFF_PRI;
  const unsigned* U = UW;
  const unsigned* encwB = U + OFF_ENCW + (size_t)b * 128 * G3;
  unsigned* XH = UW + OFF_XH + b * 256;
  unsigned* TP = UW + OFF_TP + b * 4096;
  unsigned* XE = UW + OFF_XE + b * 256;
  unsigned* FLG = UW + OFF_FLG + b * 32;

  __shared__ __align__(16) float sA[280];
  __shared__ __align__(16) unsigned sAH[128];
  __shared__ __align__(16) unsigned sXfH[40];
  __shared__ __align__(16) unsigned sHH[256];
  __shared__ __align__(16) unsigned sHsl[64];
  __shared__ __align__(16) unsigned sT1H[256];
  __shared__ __align__(16) float sHfC[128];
  __shared__ __align__(16) float sP[6 * 8 * 128];
  __shared__ __align__(16) float sG6[768];
  __shared__ __align__(16) float sFLo[512];
  __shared__ __align__(16) float sFDo[512];
  __shared__ __align__(16) float sPriL[64];
  __shared__ __align__(16) float sDk[176];
  __shared__ __align__(16) float sMask[256];
  __shared__ int sIdx[128];
  __shared__ int sNz;
  __shared__ float sRed2[8];

  for (int x = tid; x < 280; x += 1024) sA[x] = 0.f;
  for (int x = tid; x < 128; x += 1024) { sAH[x] = 0u; sHfC[x & 127] = 0.f; }
  for (int x = tid; x < 256; x += 1024) { sHH[x] = 0u;
    sMask[x] = ld_any(mask_, (long long)b * Sn + x, bf); }
  if (tid == 0) { sA[10] = 1.f; sAH[0] = pack_h2(1.f, 0.f); sIdx[0] = 0; sNz = 1; }
  if (tid < 40) sXfH[tid] = pack_h2(ld_any(gt_, (long long)b * Tn * Hn + 2 * tid, bf),
                                    ld_any(gt_, (long long)b * Tn * Hn + 2 * tid + 1, bf));
  __syncthreads();

  for (int t = 0; t < Tn; ++t) {
    const unsigned ep = (unsigned)(t + 1);
    // ---- S1: gate dots, c-range [128j,128j+128), 8-way split-k, batched loads ----
    {
      const int ks = tid >> 7, cl = tid & 127;
      const int c = (j << 7) + cl;
      float xr = 0.f, xz = 0.f, xn = 0.f, hr = 0.f, hz = 0.f, hn = 0.f;
      {  // frame: 5 jp x 3, all 15 loads hoisted
        const unsigned* pf = U + OFF_WIFPK + 3 * c;
        unsigned w[15];
        #pragma unroll
        for (int q = 0; q < 5; ++q) {
          w[3 * q]     = pf[(ks * 5 + q) * G3];
          w[3 * q + 1] = pf[(ks * 5 + q) * G3 + 1];
          w[3 * q + 2] = pf[(ks * 5 + q) * G3 + 2];
        }
        #pragma unroll
        for (int q = 0; q < 5; ++q) {
          unsigned a = sXfH[ks * 5 + q];
          xr = dot2f(w[3 * q], a, xr);
          xz = dot2f(w[3 * q + 1], a, xz);
          xn = dot2f(w[3 * q + 2], a, xn);
        }
      }
      {  // ENCW via compact nonzero-alpha list (branch-free)
        const unsigned* pe = encwB + 3 * c;
        const int m = sNz;
        for (int ii = ks; ii < m; ii += 8) {
          int kp = sIdx[ii];
          unsigned a = sAH[kp];
          unsigned w0 = pe[kp * G3], w1 = pe[kp * G3 + 1], w2 = pe[kp * G3 + 2];
          xr = dot2f(w0, a, xr);
          xz = dot2f(w1, a, xz);
          xn = dot2f(w2, a, xn);
        }
      }
      {  // WHPK: 32 kp x 3 in chunks of 8 (24 loads in flight)
        const unsigned* ph = U + OFF_WHPK + 3 * c;
        #pragma unroll
        for (int ch = 0; ch < 4; ++ch) {
          const int k0 = ks * 32 + ch * 8;
          unsigned w[24];
          #pragma unroll
          for (int q = 0; q < 8; ++q) {
            w[3 * q]     = ph[(k0 + q) * G3];
            w[3 * q + 1] = ph[(k0 + q) * G3 + 1];
            w[3 * q + 2] = ph[(k0 + q) * G3 + 2];
          }
          #pragma unroll
          for (int q = 0; q < 8; ++q) {
            unsigned a = sHH[k0 + q];
            hr = dot2f(w[3 * q], a, hr);
            hz = dot2f(w[3 * q + 1], a, hz);
            hn = dot2f(w[3 * q + 2], a, hn);
          }
        }
      }
      sP[(0 * 8 + ks) * 128 + cl] = xr;
      sP[(1 * 8 + ks) * 128 + cl] = xz;
      sP[(2 * 8 + ks) * 128 + cl] = xn;
      sP[(3 * 8 + ks) * 128 + cl] = hr;
      sP[(4 * 8 + ks) * 128 + cl] = hz;
      sP[(5 * 8 + ks) * 128 + cl] = hn;
    }
    __syncthreads();
    if (tid < 768) {
      int g = tid >> 7, cl = tid & 127;
      float s = 0.f;
      #pragma unroll
      for (int ks = 0; ks < 8; ++ks) s += sP[(g * 8 + ks) * 128 + cl];
      sG6[tid] = s;
    }
    __syncthreads();
    // ---- S2: gates | prior conv | loc conv ----
    if (tid < 128) {
      int cl = tid, c = (j << 7) + cl;
      float xr = sG6[cl] + BI[c];
      float xz = sG6[128 + cl] + BI[512 + c];
      float xn = sG6[256 + cl] + BI[1024 + c];
      float hr = sG6[384 + cl] + BH[c];
      float hz = sG6[512 + cl] + BH[512 + c];
      float hn = sG6[640 + cl] + BH[1024 + c];
      float r = fast_sigmoid(xr + hr);
      float z = fast_sigmoid(xz + hz);
      float n = fast_tanh(xn + r * hn);
      float hN = (1.f - z) * n + z * sHfC[cl];
      sHfC[cl] = hN;
      float nb = __shfl_xor(hN, 1, 64);
      if (!(tid & 1)) sHsl[tid >> 1] = pack_h2(hN, nb);
    } else if (tid >= 192 && tid < 256) {
      int sl = tid - 192;
      float acc = 0.f;
      #pragma unroll
      for (int k = 0; k < Pn; ++k) acc = fmaf(prw[k], sA[(j << 6) + sl + k], acc);
      sPriL[sl] = acc;
    } else if (tid >= 512) {
      int idx = tid - 512;
      int l = __builtin_amdgcn_readfirstlane(idx >> 6), sl = idx & 63;
      float acc = 0.f;
      #pragma unroll
      for (int k = 0; k < Kn; ++k) acc = fmaf(lw[l * Kn + k], sA[(j << 6) + sl + k], acc);
      sFLo[l * 64 + sl] = acc;
    }
    __syncthreads();
    // ---- S3: t1 partials from OWN h-slice (batched) + publish; flag A ----
    {
      const int c = tid & 511, kh = tid >> 9;
      const unsigned* m1 = U + OFF_W1PK + (unsigned)(j * 64 + kh * 32) * 512 + c;
      float acc = 0.f;
      #pragma unroll
      for (int ch = 0; ch < 2; ++ch) {
        unsigned w[16];
        #pragma unroll
        for (int q = 0; q < 16; ++q) w[q] = m1[(ch * 16 + q) * 512];
        #pragma unroll
        for (int q = 0; q < 16; ++q)
          acc = dot2f(w[q], sHsl[kh * 32 + ch * 16 + q], acc);
      }
      st_dev(&TP[(j * 2 + kh) * 512 + c], __float_as_uint(acc));
    }
    if (tid < 64) st_dev(&XH[(j << 6) + tid], sHsl[tid]);
    __syncthreads();   // per-wave vmcnt(0) drain => stores globally visible
    if (tid == 0) st_dev(&FLG[j], ep);
    if (tid < 4) {
      while (ld_dev(&FLG[tid]) < ep) __builtin_amdgcn_s_sleep(1);
    }
    __syncthreads();
    // ---- S4: full h; t1 = tanh(b1 + sum of 8 partials) ----
    if (tid < 256) sHH[tid] = ld_dev(&XH[tid]);
    if (tid < 512) {
      unsigned v[8];
      #pragma unroll
      for (int p = 0; p < 8; ++p) v[p] = ld_dev(&TP[p * 512 + tid]);
      float a = B1[tid];
      #pragma unroll
      for (int p = 0; p < 8; ++p) a += __uint_as_float(v[p]);
      float tv = fast_tanh(a);
      float nb = __shfl_xor(tv, 1, 64);
      if (!(tid & 1)) sT1H[tid >> 1] = pack_h2(tv, nb);
    }
    __syncthreads();
    // ---- S5: dkern = W2 t1 (replicated, split-k quarters, batched) ----
    if (tid < 672) {
      int kq = tid / 168, j2 = tid - kq * 168;
      const unsigned* m2 = U + OFF_W2PK + kq * 64 * 168 + j2;
      float acc = 0.f;
      #pragma unroll
      for (int ch = 0; ch < 4; ++ch) {
        unsigned w[16];
        #pragma unroll
        for (int q = 0; q < 16; ++q) w[q] = m2[(ch * 16 + q) * 168];
        #pragma unroll
        for (int q = 0; q < 16; ++q)
          acc = dot2f(w[q], sT1H[kq * 64 + ch * 16 + q], acc);
      }
      sP[tid] = acc;
    }
    __syncthreads();
    if (tid < 168) sDk[tid] = sP[tid] + sP[tid + 168] + sP[tid + 336] + sP[tid + 504];
    __syncthreads();
    // ---- S6: dynamic conv for own s-range ----
    if (tid < 512) {
      int l = __builtin_amdgcn_readfirstlane(tid >> 6), sl = tid & 63;
      float acc = 0.f;
      #pragma unroll
      for (int k = 0; k < Kn; ++k) acc = fmaf(sDk[l * Kn + k], sA[(j << 6) + sl + k], acc);
      sFDo[l * 64 + sl] = acc;
    }
    __syncthreads();
    // ---- S7: scorer partials, 16 c-slices x 64 s ----
    {
      const int sl = tid & 63;
      const int slice = __builtin_amdgcn_readfirstlane(tid >> 6);
      float fl[LOCn], fd[LOCn];
      #pragma unroll
      for (int l = 0; l < LOCn; ++l) { fl[l] = sFLo[l * 64 + sl]; fd[l] = sFDo[l * 64 + sl]; }
      float e = 0.f;
      const int c0 = slice << 4;
      for (int c = c0; c < c0 + 16; ++c) {
        float sc = dbv[c];
        #pragma unroll
        for (int l = 0; l < LOCn; ++l) {
          sc = fmaf(Pw[c * LOCn + l], fl[l], sc);
          sc = fmaf(Dw[c * LOCn + l], fd[l], sc);
        }
        e = fmaf(agg[c], fast_tanh(sc), e);
      }
      sP[slice * 64 + sl] = e;
    }
    __syncthreads();
    // ---- energy publish; flag B ----
    if (tid < 64) {
      float E = 0.f;
      #pragma unroll
      for (int q = 0; q < 16; ++q) E += sP[q * 64 + tid];
      E += fast_log(sPriL[tid] + 1e-5f);
      if (!(sMask[(j << 6) + tid] > 0.f)) E = -__builtin_inff();
      st_dev(&XE[(j << 6) + tid], __float_as_uint(E));
    }
    __builtin_amdgcn_s_waitcnt(0);
    if (tid == 0) st_dev(&FLG[16 + j], ep);
    if (tid < 4) {
      while (ld_dev(&FLG[16 + tid]) < ep) __builtin_amdgcn_s_sleep(1);
    }
    __syncthreads();
    // ---- S8: softmax (replicated) + alpha + sparse list + output ----
    float eV = -__builtin_inff(), exv = 0.f;
    if (tid < 256) {
      eV = __uint_as_float(ld_dev(&XE[tid]));
      float m = eV;
      #pragma unroll
      for (int off = 32; off > 0; off >>= 1) m = fmaxf(m, __shfl_xor(m, off, 64));
      if ((tid & 63) == 0) sRed2[tid >> 6] = m;
    }
    __syncthreads();
    if (tid < 256) {
      float M = fmaxf(fmaxf(sRed2[0], sRed2[1]), fmaxf(sRed2[2], sRed2[3]));
      exv = fast_exp(eV - M);
      float ssum = exv;
      #pragma unroll
      for (int off = 32; off > 0; off >>= 1) ssum += __shfl_xor(ssum, off, 64);
      if ((tid & 63) == 0) sRed2[4 + (tid >> 6)] = ssum;
    } else if (tid >= 512 && tid < 552 && t + 1 < Tn) {
      int i = tid - 512;
      sXfH[i] = pack_h2(ld_any(gt_, ((long long)b * Tn + t + 1) * Hn + 2 * i, bf),
                        ld_any(gt_, ((long long)b * Tn + t + 1) * Hn + 2 * i + 1, bf));
    }
    __syncthreads();
    if (tid < 256) {
      float Z = sRed2[4] + sRed2[5] + sRed2[6] + sRed2[7];
      sA[10 + tid] = exv * __builtin_amdgcn_rcpf(Z);
    }
    __syncthreads();
    if (tid < 64) {
      // pack alpha pairs + build compact nonzero index list (single wave)
      float a0 = sA[10 + 4 * tid], a1 = sA[10 + 4 * tid + 1];
      float a2 = sA[10 + 4 * tid + 2], a3 = sA[10 + 4 * tid + 3];
      unsigned p0 = pack_h2(a0, a1), p1 = pack_h2(a2, a3);
      sAH[2 * tid] = p0;
      sAH[2 * tid + 1] = p1;
      unsigned long long m0 = __ballot(p0 != 0u);
      unsigned long long m1 = __ballot(p1 != 0u);
      unsigned long long lt = (1ull << tid) - 1ull;
      int pos = __popcll(m0 & lt) + __popcll(m1 & lt);
      if (p0) sIdx[pos++] = 2 * tid;
      if (p1) sIdx[pos] = 2 * tid + 1;
      if (tid == 0) sNz = __popcll(m0) + __popcll(m1);
    } else if (tid >= 256 && tid < 320) {
      int s = (j << 6) + (tid - 256);
      float a = sA[10 + s];
      size_t oi = ((size_t)b * Tn + t) * Sn + s;
      if (bf) ((__hip_bfloat16*)out_)[oi] = __float2bfloat16(a);
      else ((float*)out_)[oi] = a;
    }
    __syncthreads();
  }
}

// ---- fallback: single-block-per-batch kernel (R3) ----
__global__ __launch_bounds__(1024) void k_single(
    const void* __restrict__ enc_, const void* __restrict__ mask_,
    const void* __restrict__ gt_, const float* __restrict__ wsf,
    const unsigned* __restrict__ U, void* __restrict__ out_, int use_encw) {
  const int b = blockIdx.x;
  const int tid = threadIdx.x;
  const int bf = ((const int*)(wsf + OFF_FLAG))[0];
  const float* BI = wsf + OFF_BI;
  const float* BH = wsf + OFF_BH;
  const float* B1 = wsf + OFF_B1;
  const float* lw = wsf + OFF_LW;
  const float* Pw = wsf + OFF_PW;
  const float* Dw = wsf + OFF_DW;
  const float* dbv = wsf + OFF_DB;
  const float* agg = wsf + OFF_AGG;
  const float* prw = wsf + OFF_PRI;

  __shared__ __align__(16) float sA[280];
  __shared__ __align__(16) unsigned sAH[128];
  __shared__ __align__(16) unsigned sXfH[40];
  __shared__ __align__(16) unsigned sPrevH[256];
  __shared__ __align__(16) float sHf[512];
  __shared__ __align__(16) unsigned sHH[256];
  __shared__ __align__(16) unsigned sT1H[256];
  __shared__ __align__(16) float sXr[512], sXz[512], sXn[512];
  __shared__ __align__(16) float sHr[512], sHz[512], sHnM[512], sHnP[512];
  __shared__ __align__(16) float sDk[176];
  __shared__ __align__(16) float sFL[LOCn][Sn];
  __shared__ __align__(16) float sFD[LOCn][Sn];
  __shared__ __align__(16) float sPri[Sn];
  __shared__ __align__(16) float sMask[Sn];
  __shared__ __align__(16) float sR[1024];
  __shared__ float sRed2[8];

  for (int x = tid; x < 280; x += 1024) sA[x] = 0.f;
  for (int x = tid; x < 128; x += 1024) sAH[x] = 0u;
  for (int x = tid; x < Cn; x += 1024) sHf[x] = 0.f;
  for (int x = tid; x < 256; x += 1024) sHH[x] = 0u;
  for (int x = tid; x < Sn; x += 1024) sMask[x] = ld_any(mask_, (long long)b * Sn + x, bf);
  if (tid == 0) { sA[Kn / 2] = 1.f; sAH[0] = pack_h2(1.f, 0.f); }
  if (tid < Hn) ((_Float16*)sXfH)[tid] = (_Float16)ld_any(gt_, (long long)b * Tn * Hn + tid, bf);
  __syncthreads();

  const int Pp = use_encw ? 132 : 0;
  const int n3 = 256 - Pp;
  const int n1 = use_encw ? 128 : 256;
  const unsigned* encwB = U + OFF_ENCW + (size_t)b * 128 * G3;

  for (int t = 0; t < Tn; ++t) {
    if (!use_encw) {
      int i = tid & (In - 1);
      int s0 = (tid >> 9) << 7;
      float acc = 0.f;
      if (bf) {
        const unsigned short* enc = (const unsigned short*)enc_ + (size_t)b * Sn * In + i;
        #pragma unroll 4
        for (int s = s0; s < s0 + 128; ++s)
          acc = fmaf(__uint_as_float(((unsigned)enc[(size_t)s * In]) << 16), sA[10 + s], acc);
      } else {
        const float* enc = (const float*)enc_ + (size_t)b * Sn * In + i;
        #pragma unroll 4
        for (int s = s0; s < s0 + 128; ++s)
          acc = fmaf(enc[(size_t)s * In], sA[10 + s], acc);
      }
      sR[tid] = acc;
      __syncthreads();
      if (tid < In) ((_Float16*)sPrevH)[tid] = (_Float16)(sR[tid] + sR[tid + In]);
      __syncthreads();
    }
    if (tid < Cn) {
      const int c = tid;
      float xr = BI[c], xz = BI[c + 512], xn = BI[c + 1024];
      {
        const unsigned* pf = U + OFF_WIFPK + 3 * c;
        #pragma unroll 4
        for (int jp = 0; jp < 40; ++jp) {
          unsigned a = sXfH[jp];
          xr = dot2f(pf[jp * G3], a, xr);
          xz = dot2f(pf[jp * G3 + 1], a, xz);
          xn = dot2f(pf[jp * G3 + 2], a, xn);
        }
      }
      {
        const unsigned* pm = use_encw ? (encwB + 3 * c) : (U + OFF_WIPREVPK + 3 * c);
        const unsigned* aSrc = use_encw ? sAH : sPrevH;
        #pragma unroll 4
        for (int kp = 0; kp < n1; ++kp) {
          unsigned a = aSrc[kp];
          xr = dot2f(pm[kp * G3], a, xr);
          xz = dot2f(pm[kp * G3 + 1], a, xz);
          xn = dot2f(pm[kp * G3 + 2], a, xn);
        }
      }
      {
        float hp = 0.f;
        const unsigned* ph = U + OFF_WHPK + 3 * c + 2;
        #pragma unroll 4
        for (int kp = n3; kp < 256; ++kp)
          hp = dot2f(ph[kp * G3], sHH[kp], hp);
        sHnP[c] = hp;
      }
      sXr[c] = xr; sXz[c] = xz; sXn[c] = xn;
    } else {
      const int c = tid - Cn;
      float hr = BH[c], hz = BH[c + 512], hn = BH[c + 1024];
      const unsigned* ph = U + OFF_WHPK + 3 * c;
      #pragma unroll 4
      for (int kp = 0; kp < n3; ++kp) {
        unsigned a = sHH[kp];
        hr = dot2f(ph[kp * G3], a, hr);
        hz = dot2f(ph[kp * G3 + 1], a, hz);
        hn = dot2f(ph[kp * G3 + 2], a, hn);
      }
      #pragma unroll 4
      for (int kp = n3; kp < 256; ++kp) {
        unsigned a = sHH[kp];
        hr = dot2f(ph[kp * G3], a, hr);
        hz = dot2f(ph[kp * G3 + 1], a, hz);
      }
      sHr[c] = hr; sHz[c] = hz; sHnM[c] = hn;
    }
    __syncthreads();
    if (tid < Cn) {
      int c = tid;
      float r = fast_sigmoid(sXr[c] + sHr[c]);
      float z = fast_sigmoid(sXz[c] + sHz[c]);
      float n = fast_tanh(sXn[c] + r * (sHnM[c] + sHnP[c]));
      float hN = (1.f - z) * n + z * sHf[c];
      sHf[c] = hN;
      ((_Float16*)sHH)[c] = (_Float16)hN;
    } else {
      int j = tid - Cn;
      #pragma unroll
      for (int rr = 0; rr < 4; ++rr) {
        int idx = j + (rr << 9);
        int l = idx >> 8, s = idx & (Sn - 1);
        float acc = 0.f;
        #pragma unroll
        for (int k = 0; k < Kn; ++k) acc = fmaf(lw[l * Kn + k], sA[s + k], acc);
        sFL[l][s] = acc;
      }
      if (j < Sn) {
        float acc = 0.f;
        #pragma unroll
        for (int k = 0; k < Pn; ++k) acc = fmaf(prw[k], sA[j + k], acc);
        sPri[j] = acc;
      }
    }
    __syncthreads();
    {
      int c = tid & (Cn - 1), half = tid >> 9;
      const unsigned* m1 = U + OFF_W1PK + half * 128 * 512 + c;
      float acc = 0.f;
      #pragma unroll 4
      for (int kp = 0; kp < 128; ++kp)
        acc = dot2f(m1[kp * 512], sHH[half * 128 + kp], acc);
      sR[tid] = acc;
    }
    __syncthreads();
    if (tid < Cn) ((_Float16*)sT1H)[tid] = (_Float16)fast_tanh(B1[tid] + sR[tid] + sR[tid + Cn]);
    __syncthreads();
    if (tid < 672) {
      int kq = tid / 168, j = tid - kq * 168;
      const unsigned* m2 = U + OFF_W2PK + kq * 64 * 168 + j;
      float acc = 0.f;
      #pragma unroll 4
      for (int kp = 0; kp < 64; ++kp)
        acc = dot2f(m2[kp * 168], sT1H[kq * 64 + kp], acc);
      sR[tid] = acc;
    }
    __syncthreads();
    if (tid < LOCn * Kn) sDk[tid] = sR[tid] + sR[tid + 168] + sR[tid + 336] + sR[tid + 504];
    __syncthreads();
    #pragma unroll
    for (int rr = 0; rr < 2; ++rr) {
      int idx = tid + (rr << 10);
      int l = idx >> 8, s = idx & (Sn - 1);
      float acc = 0.f;
      #pragma unroll
      for (int k = 0; k < Kn; ++k) acc = fmaf(sDk[l * Kn + k], sA[s + k], acc);
      sFD[l][s] = acc;
    }
    __syncthreads();
    {
      const int q = __builtin_amdgcn_readfirstlane(tid >> 8);
      const int s = tid & (Sn - 1);
      float fl0[LOCn], fd0[LOCn];
      #pragma unroll
      for (int l = 0; l < LOCn; ++l) { fl0[l] = sFL[l][s]; fd0[l] = sFD[l][s]; }
      float e = 0.f;
      const int c0 = q << 6;
      for (int c = c0; c < c0 + 64; ++c) {
        float sc = dbv[c];
        #pragma unroll
        for (int l = 0; l < LOCn; ++l) {
          sc = fmaf(Pw[c * LOCn + l], fl0[l], sc);
          sc = fmaf(Dw[c * LOCn + l], fd0[l], sc);
        }
        e = fmaf(agg[c], fast_tanh(sc), e);
      }
      sR[tid] = e;
    }
    __syncthreads();
    float eVal = -__builtin_inff();
    if (tid < Sn) {
      eVal = sR[tid] + sR[tid + 256] + sR[tid + 512] + sR[tid + 768];
      eVal += fast_log(sPri[tid] + 1e-5f);
      if (!(sMask[tid] > 0.f)) eVal = -__builtin_inff();
      float m = eVal;
      #pragma unroll
      for (int off = 32; off > 0; off >>= 1) m = fmaxf(m, __shfl_xor(m, off, 64));
      if ((tid & 63) == 0) sRed2[tid >> 6] = m;
    }
    __syncthreads();
    float exv = 0.f;
    if (tid < Sn) {
      float M = fmaxf(fmaxf(sRed2[0], sRed2[1]), fmaxf(sRed2[2], sRed2[3]));
      exv = fast_exp(eVal - M);
      float ssum = exv;
      #pragma unroll
      for (int off = 32; off > 0; off >>= 1) ssum += __shfl_xor(ssum, off, 64);
      if ((tid & 63) == 0) sRed2[4 + (tid >> 6)] = ssum;
    }
    __syncthreads();
    if (tid < Sn) {
      float Z = sRed2[4] + sRed2[5] + sRed2[6] + sRed2[7];
      float a = exv * __builtin_amdgcn_rcpf(Z);
      sA[10 + tid] = a;
      ((_Float16*)sAH)[tid] = (_Float16)a;
      size_t oi = ((size_t)b * Tn + t) * Sn + tid;
      if (bf) ((__hip_bfloat16*)out_)[oi] = __float2bfloat16(a);
      else ((float*)out_)[oi] = a;
    } else if (tid >= 512 && tid < 512 + Hn && t + 1 < Tn) {
      int j = tid - 512;
      ((_Float16*)sXfH)[j] = (_Float16)ld_any(gt_, ((long long)b * Tn + t + 1) * Hn + j, bf);
    }
    __syncthreads();
  }
}

extern "C" void kernel_launch(void* const* d_in, const int* in_sizes, int n_in,
                              void* d_out, int out_size, void* d_ws, size_t ws_size,
                              hipStream_t stream) {
  float* wsf = (float*)d_ws;
  unsigned* U = (unsigned*)d_ws;
  const int use_encw = (ws_size >= (size_t)WS_END_ENCW * 4u) ? 1 : 0;
  const int use_split = (ws_size >= (size_t)WS_END_ALL * 4u) ? 1 : 0;
  k_flag<<<1, 64, 0, stream>>>(d_in[1], wsf);
  k_prep<<<1024, 256, 0, stream>>>(d_in[3], d_in[4], d_in[5], d_in[6],
                                   d_in[7], d_in[8], d_in[9], d_in[10],
                                   d_in[11], d_in[12], d_in[13], d_in[14],
                                   d_in[15], wsf, U);
  if (use_split) {
    k_encw<<<256, 1024, 0, stream>>>(d_in[0], wsf, U);
    k_zero<<<8, 256, 0, stream>>>(U);
    k_split<<<256, 1024, 0, stream>>>(d_in[1], d_in[2], wsf, U, d_out);
  } else {
    if (use_encw) k_encw<<<256, 1024, 0, stream>>>(d_in[0], wsf, U);
    k_single<<<Bn, 1024, 0, stream>>>(d_in[0], d_in[1], d_in[2], wsf, U, d_out, use_encw);
  }
}